// Round 7
// baseline (7896.606 us; speedup 1.0000x reference)
//
#include <hip/hip_runtime.h>

// Decoder scan: B=1024, T=128, M=256, P=256, 127 steps.
// R9: per-step kernel chain. R2-R8 showed dur ~= FETCH/1.3TB/s across all
// persistent-block variants: each of 256 blocks re-pulls 768KB weights/step
// through a ~6KB in-flight window (latency x depth bound). Fix the
// architecture: per step, K_g computes gates+dW for ALL batches batch-tiled
// 128-wide (weights read 8x/step = ~6MB, not 256x = 197MB), then K_s does
// scores/softmax/LSTM with XW as bulk coalesced L3 streams. Kernel boundary
// = global sync. MFMA K-order identical to R8 (bitwise-same accumulation).

#define B_SZ 1024
#define T_SZ 128
#define M_SZ 256
#define NSTEP 127

typedef __attribute__((ext_vector_type(8))) short short8;
typedef __attribute__((ext_vector_type(4))) float f32x4;

__device__ __forceinline__ float bf2f_lo(unsigned u) {
  return __builtin_bit_cast(float, u << 16);
}
__device__ __forceinline__ float bf2f_hi(unsigned u) {
  return __builtin_bit_cast(float, u & 0xffff0000u);
}
__device__ __forceinline__ unsigned short f2bf(float f) {
  unsigned u = __builtin_bit_cast(unsigned, f);
  u = (u + 0x7fffu + ((u >> 16) & 1u)) >> 16;  // RNE
  return (unsigned short)u;
}
__device__ __forceinline__ float fexp2(float x) { return __builtin_amdgcn_exp2f(x); }
__device__ __forceinline__ float frcp(float x) { return __builtin_amdgcn_rcpf(x); }
__device__ __forceinline__ float tanh_f(float x) {
  float t = fexp2(x * 2.8853900817779268f);
  return 1.f - 2.f * frcp(t + 1.f);
}
__device__ __forceinline__ float sigm_f(float x) {
  return frcp(1.f + fexp2(x * -1.4426950408889634f));
}
__device__ __forceinline__ short8 as_s8(uint4 u) { return __builtin_bit_cast(short8, u); }

#define MFMA_BF16(a, b, c) __builtin_amdgcn_mfma_f32_16x16x32_bf16(as_s8(a), as_s8(b), c, 0, 0, 0)

// ---------------- prep: weight bf16 fragment swizzles + bias sum ----------------
__global__ void prep_w(const float* __restrict__ WU_d,
                       const float* __restrict__ W_hh,
                       const float* __restrict__ b_ih,
                       const float* __restrict__ b_hh,
                       unsigned short* __restrict__ W1F,
                       unsigned short* __restrict__ W2F,
                       unsigned short* __restrict__ WxF,
                       float* __restrict__ bsum) {
  int i = blockIdx.x * 256 + threadIdx.x;
  if (i < 131072) {
    int j = i & 7, lane = (i >> 3) & 63, ks = (i >> 9) & 15, mt = i >> 13;
    int r = lane & 15, kg = lane >> 4;
    int k = ks * 32 + kg * 8 + j;
    W1F[i] = f2bf(WU_d[(mt * 16 + r) * 768 + k]);
  } else if (i < 131072 + 262144) {
    int i2 = i - 131072;
    int j = i2 & 7, lane = (i2 >> 3) & 63, ks = (i2 >> 9) & 7, jt = i2 >> 12;
    int r = lane & 15, kg = lane >> 4;
    int k = ks * 32 + kg * 8 + j;
    W2F[i2] = f2bf(W_hh[(jt * 16 + r) * 256 + k]);
  } else if (i < 131072 + 262144 + 65536) {
    int i3 = i - (131072 + 262144);
    int j = i3 & 7, lane = (i3 >> 3) & 63, ks = (i3 >> 9) & 7, mt = i3 >> 12;
    int r = lane & 15, kg = lane >> 4;
    int k = 512 + ks * 32 + kg * 8 + j;
    WxF[i3] = f2bf(WU_d[(mt * 16 + r) * 768 + k]);
  } else if (i < 131072 + 262144 + 65536 + 1024) {
    int i4 = i - (131072 + 262144 + 65536);
    bsum[i4] = b_ih[i4] + b_hh[i4];
  }
}

// ---------------- prep: XW = X @ WU_dx^T (bf16) and XWl[b][t] = Wl[1:].X[b][t] ----------------
__global__ __launch_bounds__(256, 1) void prep_xw(
    const float* __restrict__ X,            // (T=128, B=1024, M=256) fp32
    const unsigned short* __restrict__ WxF,
    const float* __restrict__ Wl,           // 257
    unsigned short* __restrict__ XW,        // (B,T,M) bf16
    float* __restrict__ XWl) {              // (B,T) fp32
  __shared__ __align__(16) unsigned short XL[128 * 256];
  const int b = blockIdx.x, tid = threadIdx.x;
  for (int i = tid; i < 128 * 256; i += 256) {
    int t = i >> 8, k = i & 255;
    XL[i] = f2bf(X[(size_t)t * 262144 + (size_t)b * 256 + k]);
  }
  __syncthreads();
  const int wave = tid >> 6, lane = tid & 63, r = lane & 15, kg = lane >> 4;
  for (int tt = 0; tt < 8; ++tt) {
    uint4 a[8];
#pragma unroll
    for (int ks = 0; ks < 8; ++ks)
      a[ks] = *(const uint4*)&XL[(tt * 16 + r) * 256 + ks * 32 + kg * 8];
#pragma unroll
    for (int mtl = 0; mtl < 4; ++mtl) {
      const int mt = wave * 4 + mtl;
      f32x4 acc = {0.f, 0.f, 0.f, 0.f};
#pragma unroll
      for (int ks = 0; ks < 8; ++ks) {
        uint4 braw = *(const uint4*)(WxF + ((size_t)(mt * 8 + ks) * 64 + lane) * 8);
        acc = MFMA_BF16(a[ks], braw, acc);
      }
#pragma unroll
      for (int rr = 0; rr < 4; ++rr) {
        int trow = tt * 16 + kg * 4 + rr;
        XW[(size_t)b * 32768 + trow * 256 + mt * 16 + r] = f2bf(acc[rr]);
      }
    }
  }
  float wl4[4];
#pragma unroll
  for (int j = 0; j < 4; ++j) wl4[j] = Wl[1 + lane * 4 + j];
  for (int t = wave * 32; t < wave * 32 + 32; ++t) {
    uint2 q = *(const uint2*)&XL[t * 256 + lane * 4];
    float s = wl4[0] * bf2f_lo(q.x) + wl4[1] * bf2f_hi(q.x) +
              wl4[2] * bf2f_lo(q.y) + wl4[3] * bf2f_hi(q.y);
#pragma unroll
    for (int off = 1; off < 64; off <<= 1) s += __shfl_xor(s, off, 64);
    if (lane == 0) XWl[b * 128 + t] = s;
  }
}

// ---------------- init: zero hc (bf16) and c (fp32) ----------------
__global__ __launch_bounds__(1024, 4) void init_state(unsigned* __restrict__ hcU,
                                                      float* __restrict__ cf32) {
  int i = blockIdx.x * 1024 + threadIdx.x;  // 262144 threads
  hcU[i] = 0u;     // 2 bf16 zeros
  cf32[i] = 0.f;
}

// ---------------- per-step K_g: dWv + gates for ALL 1024 batches ----------------
// grid 96 x 256thr. Blocks 0..31: dW (btg=b>>2 of 8, mtg=b&3 of 4; K=512).
// Blocks 32..95: gates (btg of 8, ng of 8; K=256, h only).
__global__ __launch_bounds__(256, 2) void step_gemm(
    const unsigned short* __restrict__ hc,   // (1024, 512) bf16: [h|c]
    const unsigned short* __restrict__ W1F,
    const unsigned short* __restrict__ W2F,
    const float* __restrict__ v_d,
    unsigned* __restrict__ dWv,              // (1024, 256) packed (dW|v)
    float* __restrict__ gates) {             // (1024, 1024) fp32
  const int tid = threadIdx.x;
  const int wv = tid >> 6, lane = tid & 63, r = lane & 15, kg = lane >> 4;
  const int b = blockIdx.x;
  if (b < 32) {
    const int btg = b >> 2, mtg = b & 3;
    unsigned vpk[4];
#pragma unroll
    for (int i = 0; i < 4; ++i) vpk[i] = (unsigned)f2bf(v_d[(mtg * 4 + i) * 16 + r]) << 16;
#pragma unroll
    for (int bl = 0; bl < 2; ++bl) {
      const int bt = btg * 8 + wv * 2 + bl;
      uint4 a16[16];
#pragma unroll
      for (int ks = 0; ks < 16; ++ks)
        a16[ks] = *(const uint4*)&hc[(size_t)(bt * 16 + r) * 512 + ks * 32 + kg * 8];
#pragma unroll
      for (int mtl = 0; mtl < 4; ++mtl) {
        const int mt = mtg * 4 + mtl;
        f32x4 acc = {0.f, 0.f, 0.f, 0.f};
        const unsigned short* bp = W1F + (size_t)mt * 8192 + (size_t)lane * 8;
#pragma unroll
        for (int ks = 0; ks < 16; ++ks) {
          uint4 bw = *(const uint4*)(bp + (size_t)ks * 512);
          acc = MFMA_BF16(a16[ks], bw, acc);
        }
        const int brow = bt * 16 + kg * 4;
#pragma unroll
        for (int rr = 0; rr < 4; ++rr)
          dWv[(size_t)(brow + rr) * 256 + mt * 16 + r] = (unsigned)f2bf(acc[rr]) | vpk[mtl];
      }
    }
  } else {
    const int idx = b - 32, btg = idx >> 3, ng = idx & 7;
#pragma unroll
    for (int bl = 0; bl < 2; ++bl) {
      const int bt = btg * 8 + wv * 2 + bl;
      uint4 a8[8];
#pragma unroll
      for (int ks = 0; ks < 8; ++ks)
        a8[ks] = *(const uint4*)&hc[(size_t)(bt * 16 + r) * 512 + ks * 32 + kg * 8];
#pragma unroll
      for (int jl = 0; jl < 8; ++jl) {
        const int jt = ng * 8 + jl;
        f32x4 acc = {0.f, 0.f, 0.f, 0.f};
        const unsigned short* bp = W2F + (size_t)jt * 4096 + (size_t)lane * 8;
#pragma unroll
        for (int ks = 0; ks < 8; ++ks) {
          uint4 bw = *(const uint4*)(bp + (size_t)ks * 512);
          acc = MFMA_BF16(a8[ks], bw, acc);
        }
        const int brow = bt * 16 + kg * 4;
#pragma unroll
        for (int rr = 0; rr < 4; ++rr)
          gates[(size_t)(brow + rr) * 1024 + jt * 16 + r] = acc[rr];
      }
    }
  }
}

// ---- scores macro: 8 m-slots from one uint4 of XW + 2 uint4 of (dW|v) ----
#define XQ_USE(q_, n)                                                        \
  {                                                                          \
    uint4 dv0 = dvp[2 * (n)];                                                \
    uint4 dv1 = dvp[2 * (n) + 1];                                            \
    s0 += bf2f_hi(dv0.x) * tanh_f(bf2f_lo(dv0.x) + bf2f_lo(q_.x));           \
    s1 += bf2f_hi(dv0.y) * tanh_f(bf2f_lo(dv0.y) + bf2f_hi(q_.x));           \
    s2 += bf2f_hi(dv0.z) * tanh_f(bf2f_lo(dv0.z) + bf2f_lo(q_.y));           \
    s3 += bf2f_hi(dv0.w) * tanh_f(bf2f_lo(dv0.w) + bf2f_hi(q_.y));           \
    s0 += bf2f_hi(dv1.x) * tanh_f(bf2f_lo(dv1.x) + bf2f_lo(q_.z));           \
    s1 += bf2f_hi(dv1.y) * tanh_f(bf2f_lo(dv1.y) + bf2f_hi(q_.z));           \
    s2 += bf2f_hi(dv1.z) * tanh_f(bf2f_lo(dv1.z) + bf2f_lo(q_.w));           \
    s3 += bf2f_hi(dv1.w) * tanh_f(bf2f_lo(dv1.w) + bf2f_hi(q_.w));           \
  }

// ---------------- per-step K_s: scores + softmax + LSTM update ----------------
// grid 256 x 1024thr (16 waves, 4 batches/block; same mapping as R8 P2/P3).
__global__ __launch_bounds__(1024, 4) void step_scan(
    const unsigned short* __restrict__ XW,   // (B,T,M) bf16
    const float* __restrict__ XWl,           // (B,T) fp32
    const unsigned* __restrict__ dWv,        // (B,256) packed
    const float* __restrict__ gates,         // (B,1024) fp32
    const float* __restrict__ Yg,            // (1024,127)
    const float* __restrict__ W_ih,          // 1024
    const float* __restrict__ bsum,          // 1024
    const float* __restrict__ Wl,            // 257
    unsigned short* __restrict__ hc,         // (B,512) bf16, out
    float* __restrict__ cf32,                // (B,256) fp32, in/out
    float* __restrict__ betaG,               // (B,128) fp32 (step 126 only)
    const int step) {
  __shared__ __align__(16) unsigned dvLs[4][256];
  __shared__ __align__(16) float gLs[4][1024];
  __shared__ float xwlS[4][128];
  __shared__ float lL[4][128];
  __shared__ float ihL[1024];
  __shared__ float bsL[1024];

  const int tid = threadIdx.x;
  const int wave = tid >> 6;
  const int lane = tid & 63;
  const int b0 = blockIdx.x * 4;
  const int bb = wave >> 2;              // batch (0..3)
  const int tw = wave & 3;               // t-chunk
  const int mh = lane >> 5;              // m-half
  const int ts = tw * 32 + (lane & 31);  // owned t
  const int pp = tw * 64 + lane;         // LSTM p

  // ---- stage ----
  {
    int i = tid;  // dvv: 4*256 = 1024
    dvLs[i >> 8][i & 255] = dWv[(size_t)(b0 + (i >> 8)) * 256 + (i & 255)];
  }
#pragma unroll
  for (int k = 0; k < 4; ++k) {
    int i = k * 1024 + tid;
    gLs[i >> 10][i & 1023] = gates[(size_t)(b0 + (i >> 10)) * 1024 + (i & 1023)];
  }
  if (tid < 512) xwlS[tid >> 7][tid & 127] = XWl[(size_t)(b0 + (tid >> 7)) * 128 + (tid & 127)];
  { ihL[tid] = W_ih[tid]; bsL[tid] = bsum[tid]; }
  __syncthreads();

  // ---- scores: lane owns t=ts, 128 m (mh half); XW bulk from L3 ----
  const unsigned short* xp = XW + (size_t)(b0 + bb) * 32768 + (size_t)ts * 256 + mh * 128;
  const uint4* dvp = (const uint4*)&dvLs[bb][mh * 128];
  float s0 = 0.f, s1 = 0.f, s2 = 0.f, s3 = 0.f;
  {
    uint4 xq[8];
#pragma unroll
    for (int n = 0; n < 8; ++n) xq[n] = *(const uint4*)(xp + n * 8);
    XQ_USE(xq[0], 0) XQ_USE(xq[1], 1) XQ_USE(xq[2], 2) XQ_USE(xq[3], 3)
    XQ_USE(xq[4], 4) XQ_USE(xq[5], 5) XQ_USE(xq[6], 6) XQ_USE(xq[7], 7)
#pragma unroll
    for (int n = 0; n < 8; ++n) xq[n] = *(const uint4*)(xp + 64 + n * 8);
    XQ_USE(xq[0], 8) XQ_USE(xq[1], 9) XQ_USE(xq[2], 10) XQ_USE(xq[3], 11)
    XQ_USE(xq[4], 12) XQ_USE(xq[5], 13) XQ_USE(xq[6], 14) XQ_USE(xq[7], 15)
  }
  {
    float s = (s0 + s1) + (s2 + s3);
    s += __shfl_xor(s, 32, 64);
    if (lane < 32) lL[bb][ts] = s;
  }
  __syncthreads();

  // ---- softmax (redundant per wave, no max-sub) + LSTM ----
  {
    float l0 = lL[bb][lane], l1 = lL[bb][64 + lane];
    float e0 = fexp2(l0 * 1.4426950408889634f);
    float e1 = fexp2(l1 * 1.4426950408889634f);
    float sm = e0 + e1;
    float yt = e0 * xwlS[bb][lane] + e1 * xwlS[bb][64 + lane];
#pragma unroll
    for (int off = 1; off < 64; off <<= 1) {
      sm += __shfl_xor(sm, off, 64);
      yt += __shfl_xor(yt, off, 64);
    }
    float inv = frcp(sm);
    if (step == NSTEP - 1 && tw == 0) {
      betaG[(size_t)(b0 + bb) * 128 + lane] = e0 * inv;
      betaG[(size_t)(b0 + bb) * 128 + 64 + lane] = e1 * inv;
    }
    yt = yt * inv + Wl[0] * Yg[(size_t)(b0 + bb) * NSTEP + step];

    float c_old = cf32[(size_t)(b0 + bb) * 256 + pp];
    float ig = gLs[bb][pp] + yt * ihL[pp] + bsL[pp];
    float fg = gLs[bb][256 + pp] + yt * ihL[256 + pp] + bsL[256 + pp];
    float gg = gLs[bb][512 + pp] + yt * ihL[512 + pp] + bsL[512 + pp];
    float og = gLs[bb][768 + pp] + yt * ihL[768 + pp] + bsL[768 + pp];
    float cn = sigm_f(fg) * c_old + sigm_f(ig) * tanh_f(gg);
    float hn = sigm_f(og) * tanh_f(cn);
    cf32[(size_t)(b0 + bb) * 256 + pp] = cn;
    hc[(size_t)(b0 + bb) * 512 + pp] = f2bf(hn);
    hc[(size_t)(b0 + bb) * 512 + 256 + pp] = f2bf(cn);
  }
}

// ---------------- final: ctx from beta, output head ----------------
__global__ __launch_bounds__(1024, 4) void final_head(
    const float* __restrict__ X,             // (T,B,M) fp32
    const float* __restrict__ betaG,         // (B,128)
    const unsigned short* __restrict__ hc,   // (B,512) bf16
    const float* __restrict__ Wb_w,          // 256x512
    const float* __restrict__ Wb_b,          // 256
    const float* __restrict__ vb_w,          // 256
    const float* __restrict__ vb_b,          // 1
    float* __restrict__ outp) {              // 1024
  __shared__ __align__(16) float ctxW[4][4][256];
  __shared__ float ctxL[4][256];
  __shared__ float betaL[4][128];
  const int tid = threadIdx.x;
  const int wave = tid >> 6, lane = tid & 63;
  const int b0 = blockIdx.x * 4;
  const int bb = wave >> 2, tw = wave & 3;

  if (tid < 512) betaL[tid >> 7][tid & 127] = betaG[(size_t)(b0 + (tid >> 7)) * 128 + (tid & 127)];
  __syncthreads();

  {
    const int m4 = lane * 4;
    f32x4 c4 = {0.f, 0.f, 0.f, 0.f};
    for (int t = tw * 32; t < tw * 32 + 32; ++t) {
      float bta = betaL[bb][t];
      f32x4 x4 = *(const f32x4*)&X[(size_t)t * 262144 + (size_t)(b0 + bb) * 256 + m4];
      c4.x += bta * x4.x;
      c4.y += bta * x4.y;
      c4.z += bta * x4.z;
      c4.w += bta * x4.w;
    }
    *(f32x4*)&ctxW[bb][tw][m4] = c4;
  }
  __syncthreads();
  {
    const int lb2 = tid >> 8, lp2 = tid & 255;
    ctxL[lb2][lp2] = ctxW[lb2][0][lp2] + ctxW[lb2][1][lp2] +
                     ctxW[lb2][2][lp2] + ctxW[lb2][3][lp2];
  }
  __syncthreads();

  if (wave < 4) {
    const int m4 = lane * 4;
    float h0 = 0.f, h1 = 0.f, h2 = 0.f, h3 = 0.f;
    for (int q = 0; q < 512; ++q) {
      float hcq = (q < 256) ? bf2f_lo((unsigned)hc[(size_t)(b0 + wave) * 512 + q])
                            : ctxL[wave][q - 256];
      const float* wb = Wb_w + (size_t)m4 * 512 + q;
      h0 += hcq * wb[0];
      h1 += hcq * wb[512];
      h2 += hcq * wb[1024];
      h3 += hcq * wb[1536];
    }
    float o = (h0 + Wb_b[m4]) * vb_w[m4] + (h1 + Wb_b[m4 + 1]) * vb_w[m4 + 1] +
              (h2 + Wb_b[m4 + 2]) * vb_w[m4 + 2] + (h3 + Wb_b[m4 + 3]) * vb_w[m4 + 3];
#pragma unroll
    for (int off = 1; off < 64; off <<= 1) o += __shfl_xor(o, off, 64);
    if (lane == 0) outp[b0 + wave] = o + vb_b[0];
  }
}

extern "C" void kernel_launch(void* const* d_in, const int* in_sizes, int n_in,
                              void* d_out, int out_size, void* d_ws, size_t ws_size,
                              hipStream_t stream) {
  const float* Y = (const float*)d_in[0];
  const float* X = (const float*)d_in[1];
  const float* WU_d = (const float*)d_in[2];
  const float* v_d = (const float*)d_in[3];
  const float* Wl = (const float*)d_in[4];
  const float* W_ih = (const float*)d_in[5];
  const float* W_hh = (const float*)d_in[6];
  const float* b_ih = (const float*)d_in[7];
  const float* b_hh = (const float*)d_in[8];
  const float* Wb_w = (const float*)d_in[9];
  const float* Wb_b = (const float*)d_in[10];
  const float* vb_w = (const float*)d_in[11];
  const float* vb_b = (const float*)d_in[12];

  char* ws = (char*)d_ws;
  unsigned short* XW = (unsigned short*)(ws + 0);            // 64 MB
  float* XWl = (float*)(ws + 67108864);                      // 512 KB
  unsigned short* W1F = (unsigned short*)(ws + 67633152);    // 256 KB
  unsigned short* W2F = (unsigned short*)(ws + 67895296);    // 512 KB
  unsigned short* WxF = (unsigned short*)(ws + 68419584);    // 128 KB
  float* bsum = (float*)(ws + 68550656);                     // 4 KB
  unsigned short* hc = (unsigned short*)(ws + 68554752);     // 1 MB
  float* cf32 = (float*)(ws + 69603328);                     // 1 MB
  unsigned* dWv = (unsigned*)(ws + 70651904);                // 1 MB
  float* gates = (float*)(ws + 71700480);                    // 4 MB
  float* betaG = (float*)(ws + 75894784);                    // 512 KB

  prep_w<<<1796, 256, 0, stream>>>(WU_d, W_hh, b_ih, b_hh, W1F, W2F, WxF, bsum);
  prep_xw<<<1024, 256, 0, stream>>>(X, WxF, Wl, XW, XWl);
  init_state<<<256, 1024, 0, stream>>>((unsigned*)hc, cf32);

  for (int s = 0; s < NSTEP; ++s) {
    step_gemm<<<96, 256, 0, stream>>>(hc, W1F, W2F, v_d, dWv, gates);
    step_scan<<<256, 1024, 0, stream>>>(XW, XWl, dWv, gates, Y, W_ih, bsum, Wl,
                                        hc, cf32, betaG, s);
  }
  final_head<<<256, 1024, 0, stream>>>(X, betaG, hc, Wb_w, Wb_b, vb_w, vb_b,
                                       (float*)d_out);
}